// Round 12
// baseline (188.510 us; speedup 1.0000x reference)
//
#include <hip/hip_runtime.h>
#include <stdint.h>

typedef __attribute__((ext_vector_type(8))) short bf16x8;
typedef __attribute__((ext_vector_type(4))) float f32x4;
typedef __attribute__((ext_vector_type(4))) unsigned short u16x4;
typedef __attribute__((ext_vector_type(4))) unsigned int u32x4;

#define NB 32
#define HH 128
#define WW 128
#define CI 128
#define CO 128
#define HO 126
#define WO 126
#define TH 16
#define TW 16
#define PHh 18
#define PWw 18
#define NROW (PHh * PWw)   // 324 patch rows
#define RSTR 72            // shorts per LDS row (144 B): affine immediates only
#define RSTRB 144

__device__ __forceinline__ unsigned short f2bf(float f) {
  union { float f; unsigned u; } x; x.f = f;
  unsigned u = x.u;
  u += 0x7FFFu + ((u >> 16) & 1u);   // RNE round to bf16
  return (unsigned short)(u >> 16);
}

// cvt_pk_bf16_f32: RNE, packs 2 f32 -> 2 bf16 in one VALU op (no builtin on gfx950)
__device__ __forceinline__ unsigned cvtpk_bf16(float a, float b) {
  unsigned r;
  asm("v_cvt_pk_bf16_f32 %0, %1, %2" : "=v"(r) : "v"(a), "v"(b));
  return r;  // low16 = bf16(a), high16 = bf16(b)
}

// prep: [b,p][ci][co] f32 -> fragment-blocked bf16, slice-major [b][ch][p][kc]:
//   slice = (ch*9+p)*2+kc (4096 shorts each); within: f*512 + lane*8 + e
//   holds kin[b,p][ci = ch*64+kc*32+(lane>>4)*8+e][co = (f>>2)*64+(f&3)*16+(lane&15)]
__global__ void prep_kt(const float* __restrict__ kin, unsigned short* __restrict__ ktr) {
  __shared__ unsigned short t[CI * CO];  // 32 KB
  int bp = blockIdx.x;  // b*9+p, 0..287
  int b = bp / 9, p = bp % 9;
  const float* src = kin + (size_t)bp * (CI * CO);
  unsigned short* dstb = ktr + (size_t)b * (9 * CI * CO);
  for (int i = threadIdx.x; i < CI * CO / 4; i += blockDim.x) {
    f32x4 v = *(const f32x4*)(src + i * 4);
    u16x4 o;
    o.x = f2bf(v.x); o.y = f2bf(v.y); o.z = f2bf(v.z); o.w = f2bf(v.w);
    *(u16x4*)&t[i * 4] = o;
  }
  __syncthreads();
  for (int j = threadIdx.x; j < 2048; j += blockDim.x) {  // j = (sl*8+f)*64+lane
    int lane = j & 63, f = (j >> 6) & 7, sl = j >> 9;     // sl = ch*2+kc
    int ch = sl >> 1, kc = sl & 1;
    int co = (f >> 2) * 64 + (f & 3) * 16 + (lane & 15);
    int ci0 = ch * 64 + kc * 32 + (lane >> 4) * 8;
    bf16x8 v;
#pragma unroll
    for (int e = 0; e < 8; ++e) v[e] = t[(ci0 + e) * CO + co];
    int slice = (ch * 9 + p) * 2 + kc;
    *(bf16x8*)&dstb[(size_t)slice * 4096 + f * 512 + lane * 8] = v;
  }
}

// naive fallback (only if ws_size too small — not expected on this harness)
__global__ void conv_naive(const float* __restrict__ X, const float* __restrict__ Kf,
                           float* __restrict__ out) {
  int idx = blockIdx.x * blockDim.x + threadIdx.x;           // over B*HO*WO*CO
  if (idx >= NB * HO * WO * CO) return;
  int co = idx & 127, t = idx >> 7;
  int wp = t % WO; t /= WO;
  int hp = t % HO; int b = t / HO;
  const float* xb = X + (size_t)b * HH * WW * CI;
  const float* kb = Kf + (size_t)b * 9 * CI * CO;
  float s = 0.f;
  for (int p = 0; p < 9; ++p) {
    int kh = p / 3, kw = p % 3;
    const float* xr = xb + ((size_t)(hp + kh) * WW + (wp + kw)) * CI;
    const float* kr = kb + (size_t)p * CI * CO + co;
    for (int ci = 0; ci < CI; ++ci) s += xr[ci] * kr[(size_t)ci * CO];
  }
  out[idx] = s;
}

// Persistent 1-block/CU (93 KB LDS), 512 thr = 2 waves/SIMD, 256 regs/thread.
// R12: B-fragment prefetch deepened to DISTANCE 2 (Hf ring-of-3, 48 regs) —
// R11's distance-1 gave only ~310 cyc slack vs B's ~400-600 cyc L3 latency
// (B is L2-thrashed by the 21 MB/XCD X stream), so both waves of each SIMD
// stalled every cluster (MfmaUtil pinned 36%). Stage writes also move to
// s=5/11 (5-6 cluster load->use gap, covers HBM on the X stream).
__global__ __launch_bounds__(512, 2) void conv_main(
    const float* __restrict__ X, const unsigned short* __restrict__ Kt,
    float* __restrict__ out) {
  __shared__ unsigned short lds_a[2][NROW * RSTR];  // 2 x 46656 B = 93312 B

  const int tid = threadIdx.x;
  const int lane = tid & 63;
  const int wid = tid >> 6;            // 8 waves, 4 (h) x 2 (co)
  const int wr = wid >> 1, wc = wid & 1;
  const int ks = lane >> 4, lr = lane & 15;

  // block -> (xcd, batch, column): b fixed, wt fixed, ht swept 0..7
  const int bx = blockIdx.x;           // 0..255
  const int xcd = bx & 7, v = bx >> 3; // v: 0..31
  const int b = xcd * 4 + (v >> 3);    // 4 batches per XCD
  const int wt = v & 7;
  const int w0 = wt * TW;

  const float* xb = X + (size_t)b * HH * WW * CI;

  // ---- stage constants: granule i (i=0..5) = 8 ci, one b128 LDS write ----
  // slot s = tid + 512*i; row = (tid>>3)+64i; ci8 = tid&7. b128 writes at
  // pad-144: bank-group (9r+c) mod 8 bijective per row -> balanced.
  const int ci8 = tid & 7;
  unsigned okw = 0;
  int hI[6]; unsigned baseI[6];
#pragma unroll
  for (int i = 0; i < 6; ++i) {
    int row = (tid >> 3) + 64 * i;
    int h = row / PWw, w = row - PWw * h;
    int gw = w0 + w;
    if (gw < WW) okw |= (1u << i);
    hI[i] = h;
    baseI[i] = (unsigned)((h * WW + (gw & 127)) * CI + ci8 * 8);  // f32 elems
  }
  const int dst0 = (tid >> 3) * RSTR + ci8 * 8;   // shorts; granule i adds i*4608

  auto sIssue = [&](int i, int h0n, int chn, f32x4& ga, f32x4& gb) {
    bool live = (i < 5) | (tid < 32);
    bool ok = live && ((okw >> i) & 1) && (h0n + hI[i] < HH);
    const float* sp = xb + (ok ? baseI[i] + (unsigned)(h0n << 14) + (unsigned)(chn << 6)
                               : (unsigned)(ci8 << 3));
    ga = *(const f32x4*)sp;
    gb = *(const f32x4*)(sp + 4);
  };
  auto sWrite = [&](int i, int h0n, unsigned short* wbuf, const f32x4& ga, const f32x4& gb) {
    bool live = (i < 5) | (tid < 32);
    if (!live) return;
    bool ok = ((okw >> i) & 1) && (h0n + hI[i] < HH);
    u32x4 o;
    o.x = ok ? cvtpk_bf16(ga.x, ga.y) : 0u;
    o.y = ok ? cvtpk_bf16(ga.z, ga.w) : 0u;
    o.z = ok ? cvtpk_bf16(gb.x, gb.y) : 0u;
    o.w = ok ? cvtpk_bf16(gb.z, gb.w) : 0u;
    *(u32x4*)&wbuf[dst0 + i * 4608] = o;
  };

  // ---- compute: af byte = aoff + ((m+kh)*18 + kw)*144 + kc*64 (imm) ----
  const int aoff = ((wr * 4) * PWw + lr) * RSTRB + ks * 16;

  const unsigned short* ktw = Kt + (size_t)b * 9 * CI * CO + (wc * 4) * 512 + lane * 8;
  bf16x8 Hf[3][4];                     // ring-of-3: distance-2 B prefetch
  bf16x8 af[2][4];                     // distance-1 A prefetch (LDS, short lat)
  auto loadB = [&](bf16x8 (&dst)[4], const unsigned short* p) {
#pragma unroll
    for (int n = 0; n < 4; ++n)
      dst[n] = *(const bf16x8*)(p + n * 512);
  };
  auto issueAf = [&](bf16x8 (&dst)[4], int s, const char* rb) {
    const int kh = s / 6, jj = s % 6;
    const int kw = jj >> 1, kc = jj & 1;
#pragma unroll
    for (int m = 0; m < 4; ++m)
      dst[m] = *(const bf16x8*)(rb + aoff +
                                ((m + kh) * PWw * RSTRB + kw * RSTRB + kc * 64));
  };

  f32x4 zero = {0.f, 0.f, 0.f, 0.f};
  f32x4 acc[4][4];
#pragma unroll
  for (int m = 0; m < 4; ++m)
#pragma unroll
    for (int n = 0; n < 4; ++n) acc[m][n] = zero;
  auto mma = [&](bf16x8 (&a)[4], bf16x8 (&h)[4]) {
    __builtin_amdgcn_s_setprio(1);
#pragma unroll
    for (int m = 0; m < 4; ++m)
#pragma unroll
      for (int n = 0; n < 4; ++n)
        acc[m][n] = __builtin_amdgcn_mfma_f32_16x16x32_bf16(a[m], h[n], acc[m][n], 0, 0, 0);
    __builtin_amdgcn_s_setprio(0);
  };

  unsigned short* const A0 = &lds_a[0][0];
  unsigned short* const A1 = &lds_a[1][0];
  float* const ob = out + (size_t)b * HO * WO * CO;

  // ---- prologue: stage pass-0 (tile 0, ch 0) into A0; prefetch B slices 0,1 ----
  {
    f32x4 a0, b0, a1, b1, a2, b2;
    sIssue(0, 0, 0, a0, b0); sIssue(1, 0, 0, a1, b1); sIssue(2, 0, 0, a2, b2);
    sWrite(0, 0, A0, a0, b0); sWrite(1, 0, A0, a1, b1); sWrite(2, 0, A0, a2, b2);
    sIssue(3, 0, 0, a0, b0); sIssue(4, 0, 0, a1, b1); sIssue(5, 0, 0, a2, b2);
    sWrite(3, 0, A0, a0, b0); sWrite(4, 0, A0, a1, b1); sWrite(5, 0, A0, a2, b2);
  }
  loadB(Hf[0], ktw);
  loadB(Hf[1], ktw + 4096);
  __syncthreads();

  f32x4 g0a, g0b, g1a, g1b, g2a, g2b;  // 3 stage granules in flight (24 regs)

#pragma unroll 1
  for (int k = 0; k < 16; ++k) {       // 16 half-passes (8 tiles x 2 ci-halves)
    const int ch = k & 1;
    const int h0 = (k >> 1) * TH;
    unsigned short* rbuf = ch ? A1 : A0;
    unsigned short* wbuf = ch ? A0 : A1;
    const unsigned short* bq = ktw + (size_t)ch * 73728;   // ch*18*4096 shorts
    const bool stg = (k < 15);
    const int chn = (k + 1) & 1;
    const int h0n = ((k + 1) >> 1) * TH;
    const unsigned short* bqn = ktw + (size_t)chn * 73728; // next pass B base
    const char* rb = (const char*)rbuf;

    issueAf(af[0], 0, rb);             // prime A-side
#pragma unroll
    for (int s = 0; s < 18; ++s) {     // all indices compile-time (unrolled)
      // B prefetch, distance 2 (ring-of-3)
      if (s < 16) loadB(Hf[(s + 2) % 3], bq + (size_t)(s + 2) * 4096);
      else if (stg) loadB(Hf[(s + 2) % 3], bqn + (size_t)(s - 16) * 4096);
      // A prefetch, distance 1
      if (s < 17) issueAf(af[(s + 1) & 1], s + 1, rb);
      // stage loads for next half-pass (consumed 5-6 clusters later)
      if (stg && s == 0) {
        sIssue(0, h0n, chn, g0a, g0b);
        sIssue(1, h0n, chn, g1a, g1b);
        sIssue(2, h0n, chn, g2a, g2b);
      }
      mma(af[s & 1], Hf[s % 3]);
      if (stg && s == 5) {             // write 0..2, issue 3..5
        sWrite(0, h0n, wbuf, g0a, g0b);
        sWrite(1, h0n, wbuf, g1a, g1b);
        sWrite(2, h0n, wbuf, g2a, g2b);
        sIssue(3, h0n, chn, g0a, g0b);
        sIssue(4, h0n, chn, g1a, g1b);
        sIssue(5, h0n, chn, g2a, g2b);
      }
      if (stg && s == 11) {            // write 3..5
        sWrite(3, h0n, wbuf, g0a, g0b);
        sWrite(4, h0n, wbuf, g1a, g1b);
        sWrite(5, h0n, wbuf, g2a, g2b);
      }
    }

    if (ch) {                          // tile done: epilogue + acc reset
#pragma unroll
      for (int m = 0; m < 4; ++m) {
        int hp = h0 + wr * 4 + m;
        if (hp >= HO) continue;
#pragma unroll
        for (int r = 0; r < 4; ++r) {
          int wp = w0 + ks * 4 + r;
          if (wp >= WO) continue;
#pragma unroll
          for (int n = 0; n < 4; ++n) {
            int co = wc * 64 + n * 16 + lr;
            ob[((size_t)hp * WO + wp) * CO + co] = acc[m][n][r];
          }
        }
      }
#pragma unroll
      for (int m = 0; m < 4; ++m)
#pragma unroll
        for (int n = 0; n < 4; ++n) acc[m][n] = zero;
    }
    if (k < 15) __syncthreads();       // stage(k+1) visible; WAR on rbuf safe
  }
}

extern "C" void kernel_launch(void* const* d_in, const int* in_sizes, int n_in,
                              void* d_out, int out_size, void* d_ws, size_t ws_size,
                              hipStream_t stream) {
  const float* X = (const float*)d_in[0];
  const float* Kf = (const float*)d_in[1];
  float* out = (float*)d_out;
  size_t need = (size_t)NB * 9 * CI * CO * sizeof(unsigned short);  // 9.4 MB
  if (d_ws != nullptr && ws_size >= need) {
    unsigned short* ktr = (unsigned short*)d_ws;
    prep_kt<<<dim3(NB * 9), 256, 0, stream>>>(Kf, ktr);
    conv_main<<<dim3(256), 512, 0, stream>>>(X, ktr, out);
  } else {
    int total = NB * HO * WO * CO;
    conv_naive<<<(total + 255) / 256, 256, 0, stream>>>(X, Kf, out);
  }
}

// Round 13
// 178.211 us; speedup vs baseline: 1.0578x; 1.0578x over previous
//
#include <hip/hip_runtime.h>
#include <stdint.h>

typedef __attribute__((ext_vector_type(8))) short bf16x8;
typedef __attribute__((ext_vector_type(4))) float f32x4;
typedef __attribute__((ext_vector_type(4))) unsigned short u16x4;
typedef __attribute__((ext_vector_type(4))) unsigned int u32x4;

#define NB 32
#define HH 128
#define WW 128
#define CI 128
#define CO 128
#define HO 126
#define WO 126
#define TH 16
#define TW 16
#define PHh 18
#define PWw 18
#define NROW (PHh * PWw)   // 324 patch rows
#define RSTR 72            // shorts per LDS row (144 B): affine immediates only
#define RSTRB 144

__device__ __forceinline__ unsigned short f2bf(float f) {
  union { float f; unsigned u; } x; x.f = f;
  unsigned u = x.u;
  u += 0x7FFFu + ((u >> 16) & 1u);   // RNE round to bf16
  return (unsigned short)(u >> 16);
}

// cvt_pk_bf16_f32: RNE, packs 2 f32 -> 2 bf16 in one VALU op (no builtin on gfx950)
__device__ __forceinline__ unsigned cvtpk_bf16(float a, float b) {
  unsigned r;
  asm("v_cvt_pk_bf16_f32 %0, %1, %2" : "=v"(r) : "v"(a), "v"(b));
  return r;  // low16 = bf16(a), high16 = bf16(b)
}

// prep: [b,p][ci][co] f32 -> fragment-blocked bf16, slice-major [b][ch][p][kc]:
//   slice = (ch*9+p)*2+kc (4096 shorts each); within: f*512 + lane*8 + e
//   holds kin[b,p][ci = ch*64+kc*32+(lane>>4)*8+e][co = (f>>2)*64+(f&3)*16+(lane&15)]
//   note co-group g (16 co) = frag index f (g = (f>>2)*4 + (f&3) = f).
__global__ void prep_kt(const float* __restrict__ kin, unsigned short* __restrict__ ktr) {
  __shared__ unsigned short t[CI * CO];  // 32 KB
  int bp = blockIdx.x;  // b*9+p, 0..287
  int b = bp / 9, p = bp % 9;
  const float* src = kin + (size_t)bp * (CI * CO);
  unsigned short* dstb = ktr + (size_t)b * (9 * CI * CO);
  for (int i = threadIdx.x; i < CI * CO / 4; i += blockDim.x) {
    f32x4 v = *(const f32x4*)(src + i * 4);
    u16x4 o;
    o.x = f2bf(v.x); o.y = f2bf(v.y); o.z = f2bf(v.z); o.w = f2bf(v.w);
    *(u16x4*)&t[i * 4] = o;
  }
  __syncthreads();
  for (int j = threadIdx.x; j < 2048; j += blockDim.x) {  // j = (sl*8+f)*64+lane
    int lane = j & 63, f = (j >> 6) & 7, sl = j >> 9;     // sl = ch*2+kc
    int ch = sl >> 1, kc = sl & 1;
    int co = (f >> 2) * 64 + (f & 3) * 16 + (lane & 15);
    int ci0 = ch * 64 + kc * 32 + (lane >> 4) * 8;
    bf16x8 v;
#pragma unroll
    for (int e = 0; e < 8; ++e) v[e] = t[(ci0 + e) * CO + co];
    int slice = (ch * 9 + p) * 2 + kc;
    *(bf16x8*)&dstb[(size_t)slice * 4096 + f * 512 + lane * 8] = v;
  }
}

// naive fallback (only if ws_size too small — not expected on this harness)
__global__ void conv_naive(const float* __restrict__ X, const float* __restrict__ Kf,
                           float* __restrict__ out) {
  int idx = blockIdx.x * blockDim.x + threadIdx.x;           // over B*HO*WO*CO
  if (idx >= NB * HO * WO * CO) return;
  int co = idx & 127, t = idx >> 7;
  int wp = t % WO; t /= WO;
  int hp = t % HO; int b = t / HO;
  const float* xb = X + (size_t)b * HH * WW * CI;
  const float* kb = Kf + (size_t)b * 9 * CI * CO;
  float s = 0.f;
  for (int p = 0; p < 9; ++p) {
    int kh = p / 3, kw = p % 3;
    const float* xr = xb + ((size_t)(hp + kh) * WW + (wp + kw)) * CI;
    const float* kr = kb + (size_t)p * CI * CO + co;
    for (int ci = 0; ci < CI; ++ci) s += xr[ci] * kr[(size_t)ci * CO];
  }
  out[idx] = s;
}

// Persistent 1-block/CU, 512 thr = 2 waves/SIMD. R13: wave output slab
// reshaped m4xn4 -> m8xn2 (waves 2 wr x 4 wc). Per cluster per CU the B
// vector-memory traffic halves (32->16 KB: dup factor 4->2) — the measured
// 1558 cyc/round is ~3x every computed pipe EXCEPT the L1/TCP B-return path
// (~64 B/cyc => ~512+ cyc for 32 KB), which also explains why B-prefetch
// depth (R11/R12) and desync (R6) were null: bandwidth, not latency. The
// cost — af LDS reads double to 64 KB/cluster — lands on the LDS pipe
// (separate, 128 B/cyc, was only ~20% loaded). acc stays 64 regs (8x2).
__global__ __launch_bounds__(512, 2) void conv_main(
    const float* __restrict__ X, const unsigned short* __restrict__ Kt,
    float* __restrict__ out) {
  __shared__ unsigned short lds_a[2][NROW * RSTR];  // 2 x 46656 B = 93312 B

  const int tid = threadIdx.x;
  const int lane = tid & 63;
  const int wid = tid >> 6;            // 8 waves, 2 (h) x 4 (co)
  const int wr = wid >> 2, wc = wid & 3;
  const int ks = lane >> 4, lr = lane & 15;

  // block -> (xcd, batch, column): b fixed, wt fixed, ht swept 0..7
  const int bx = blockIdx.x;           // 0..255
  const int xcd = bx & 7, v = bx >> 3; // v: 0..31
  const int b = xcd * 4 + (v >> 3);    // 4 batches per XCD
  const int wt = v & 7;
  const int w0 = wt * TW;

  const float* xb = X + (size_t)b * HH * WW * CI;

  // ---- stage constants: granule i (i=0..5) = 8 ci, one b128 LDS write ----
  const int ci8 = tid & 7;
  unsigned okw = 0;
  int hI[6]; unsigned baseI[6];
#pragma unroll
  for (int i = 0; i < 6; ++i) {
    int row = (tid >> 3) + 64 * i;
    int h = row / PWw, w = row - PWw * h;
    int gw = w0 + w;
    if (gw < WW) okw |= (1u << i);
    hI[i] = h;
    baseI[i] = (unsigned)((h * WW + (gw & 127)) * CI + ci8 * 8);  // f32 elems
  }
  const int dst0 = (tid >> 3) * RSTR + ci8 * 8;   // shorts; granule i adds i*4608

  auto sIssue = [&](int i, int h0n, int chn, f32x4& ga, f32x4& gb) {
    bool live = (i < 5) | (tid < 32);
    bool ok = live && ((okw >> i) & 1) && (h0n + hI[i] < HH);
    const float* sp = xb + (ok ? baseI[i] + (unsigned)(h0n << 14) + (unsigned)(chn << 6)
                               : (unsigned)(ci8 << 3));
    ga = *(const f32x4*)sp;
    gb = *(const f32x4*)(sp + 4);
  };
  auto sWrite = [&](int i, int h0n, unsigned short* wbuf, const f32x4& ga, const f32x4& gb) {
    bool live = (i < 5) | (tid < 32);
    if (!live) return;
    bool ok = ((okw >> i) & 1) && (h0n + hI[i] < HH);
    u32x4 o;
    o.x = ok ? cvtpk_bf16(ga.x, ga.y) : 0u;
    o.y = ok ? cvtpk_bf16(ga.z, ga.w) : 0u;
    o.z = ok ? cvtpk_bf16(gb.x, gb.y) : 0u;
    o.w = ok ? cvtpk_bf16(gb.z, gb.w) : 0u;
    *(u32x4*)&wbuf[dst0 + i * 4608] = o;
  };

  // ---- compute: af byte = aoff + ((m+kh)*18 + kw)*144 + kc*64 (imm) ----
  const int aoff = ((wr * 8) * PWw + lr) * RSTRB + ks * 16;

  // B: wave wc needs co-groups wc*2, wc*2+1 = frags f = wc*2 +{0,1}:
  // one contiguous 1 KB burst per slice per wave (2 KB -> 2x b128/lane).
  const unsigned short* ktw = Kt + (size_t)b * 9 * CI * CO + (wc * 2) * 512 + lane * 8;
  bf16x8 Hf[3][2];                     // ring-of-3: distance-2 B prefetch
  auto loadB = [&](bf16x8 (&dst)[2], const unsigned short* p) {
#pragma unroll
    for (int n = 0; n < 2; ++n)
      dst[n] = *(const bf16x8*)(p + n * 512);
  };

  f32x4 zero = {0.f, 0.f, 0.f, 0.f};
  f32x4 acc[8][2];
#pragma unroll
  for (int m = 0; m < 8; ++m)
#pragma unroll
    for (int n = 0; n < 2; ++n) acc[m][n] = zero;

  unsigned short* const A0 = &lds_a[0][0];
  unsigned short* const A1 = &lds_a[1][0];
  float* const ob = out + (size_t)b * HO * WO * CO;

  // ---- prologue: stage pass-0 (tile 0, ch 0) into A0; prefetch B slices 0,1 ----
  {
    f32x4 a0, b0, a1, b1, a2, b2;
    sIssue(0, 0, 0, a0, b0); sIssue(1, 0, 0, a1, b1); sIssue(2, 0, 0, a2, b2);
    sWrite(0, 0, A0, a0, b0); sWrite(1, 0, A0, a1, b1); sWrite(2, 0, A0, a2, b2);
    sIssue(3, 0, 0, a0, b0); sIssue(4, 0, 0, a1, b1); sIssue(5, 0, 0, a2, b2);
    sWrite(3, 0, A0, a0, b0); sWrite(4, 0, A0, a1, b1); sWrite(5, 0, A0, a2, b2);
  }
  loadB(Hf[0], ktw);
  loadB(Hf[1], ktw + 4096);
  __syncthreads();

  f32x4 g0a, g0b, g1a, g1b, g2a, g2b;  // 3 stage granules in flight (24 regs)

#pragma unroll 1
  for (int k = 0; k < 16; ++k) {       // 16 half-passes (8 tiles x 2 ci-halves)
    const int ch = k & 1;
    const int h0 = (k >> 1) * TH;
    unsigned short* rbuf = ch ? A1 : A0;
    unsigned short* wbuf = ch ? A0 : A1;
    const unsigned short* bq = ktw + (size_t)ch * 73728;   // ch*18*4096 shorts
    const bool stg = (k < 15);
    const int chn = (k + 1) & 1;
    const int h0n = ((k + 1) >> 1) * TH;
    const unsigned short* bqn = ktw + (size_t)chn * 73728; // next pass B base
    const char* rb = (const char*)rbuf;

#pragma unroll
    for (int s = 0; s < 18; ++s) {     // all indices compile-time (unrolled)
      // B prefetch, distance 2 (ring-of-3)
      if (s < 16) loadB(Hf[(s + 2) % 3], bq + (size_t)(s + 2) * 4096);
      else if (stg) loadB(Hf[(s + 2) % 3], bqn + (size_t)(s - 16) * 4096);
      // stage loads for next half-pass (consumed 5-6 clusters later)
      if (stg && s == 0) {
        sIssue(0, h0n, chn, g0a, g0b);
        sIssue(1, h0n, chn, g1a, g1b);
        sIssue(2, h0n, chn, g2a, g2b);
      }
      // af reads for THIS cluster (single-buffered: R9 proved dbuf null;
      // the co-resident wave's MFMAs cover the lgkmcnt tail)
      {
        const int kh = s / 6, jj = s % 6;
        const int kw = jj >> 1, kc = jj & 1;
        bf16x8 af[8];
#pragma unroll
        for (int m = 0; m < 8; ++m)
          af[m] = *(const bf16x8*)(rb + aoff +
                                   ((m + kh) * PWw * RSTRB + kw * RSTRB + kc * 64));
        __builtin_amdgcn_s_setprio(1);
#pragma unroll
        for (int m = 0; m < 8; ++m)
#pragma unroll
          for (int n = 0; n < 2; ++n)
            acc[m][n] = __builtin_amdgcn_mfma_f32_16x16x32_bf16(af[m], Hf[s % 3][n],
                                                                acc[m][n], 0, 0, 0);
        __builtin_amdgcn_s_setprio(0);
      }
      if (stg && s == 5) {             // write 0..2, issue 3..5
        sWrite(0, h0n, wbuf, g0a, g0b);
        sWrite(1, h0n, wbuf, g1a, g1b);
        sWrite(2, h0n, wbuf, g2a, g2b);
        sIssue(3, h0n, chn, g0a, g0b);
        sIssue(4, h0n, chn, g1a, g1b);
        sIssue(5, h0n, chn, g2a, g2b);
      }
      if (stg && s == 11) {            // write 3..5
        sWrite(3, h0n, wbuf, g0a, g0b);
        sWrite(4, h0n, wbuf, g1a, g1b);
        sWrite(5, h0n, wbuf, g2a, g2b);
      }
    }

    if (ch) {                          // tile done: epilogue + acc reset
#pragma unroll
      for (int m = 0; m < 8; ++m) {
        int hp = h0 + wr * 8 + m;
        if (hp >= HO) continue;
#pragma unroll
        for (int r = 0; r < 4; ++r) {
          int wp = w0 + ks * 4 + r;
          if (wp >= WO) continue;
#pragma unroll
          for (int n = 0; n < 2; ++n) {
            int co = wc * 32 + n * 16 + lr;
            ob[((size_t)hp * WO + wp) * CO + co] = acc[m][n][r];
          }
        }
      }
#pragma unroll
      for (int m = 0; m < 8; ++m)
#pragma unroll
        for (int n = 0; n < 2; ++n) acc[m][n] = zero;
    }
    if (k < 15) __syncthreads();       // stage(k+1) visible; WAR on rbuf safe
  }
}

extern "C" void kernel_launch(void* const* d_in, const int* in_sizes, int n_in,
                              void* d_out, int out_size, void* d_ws, size_t ws_size,
                              hipStream_t stream) {
  const float* X = (const float*)d_in[0];
  const float* Kf = (const float*)d_in[1];
  float* out = (float*)d_out;
  size_t need = (size_t)NB * 9 * CI * CO * sizeof(unsigned short);  // 9.4 MB
  if (d_ws != nullptr && ws_size >= need) {
    unsigned short* ktr = (unsigned short*)d_ws;
    prep_kt<<<dim3(NB * 9), 256, 0, stream>>>(Kf, ktr);
    conv_main<<<dim3(256), 512, 0, stream>>>(X, ktr, out);
  } else {
    int total = NB * HO * WO * CO;
    conv_naive<<<(total + 255) / 256, 256, 0, stream>>>(X, Kf, out);
  }
}